// Round 1
// baseline (74.508 us; speedup 1.0000x reference)
//
#include <hip/hip_runtime.h>
#include <math.h>

// Problem: x,y,z each (4, 256, 32, 32, 32) fp32.
// Per (b,c): S = sum over 2x2x2 windows of max(window) + total_sum/8.
// pooled[b,c] = (Sx+Sy)^2 + (Sy+Sz)^2 + (Sx+Sz)^2
// out[b,:] = pooled[b,:] / max(||pooled[b,:]||_2, 1e-12)

#define BC_TOTAL 1024          // 4 * 256
#define SLICE_ELEMS 32768      // 32*32*32

__global__ __launch_bounds__(256) void pool_sum_kernel(
    const float* __restrict__ x,
    const float* __restrict__ y,
    const float* __restrict__ z,
    float* __restrict__ ws)
{
    const int bc = blockIdx.x;      // 0..1023  -> (b,c) slice
    const int which = blockIdx.y;   // 0..2     -> input select
    const float* __restrict__ p =
        (which == 0 ? x : (which == 1 ? y : z)) + (size_t)bc * SLICE_ELEMS;

    const int t = threadIdx.x;
    float acc = 0.0f;

    // Work items: (wh, ww, d4) = 16 * 16 * 8 = 2048 ; 8 per thread.
    // Each item: 2x2 (h,w) corner rows, float4 along D covering 2 windows.
#pragma unroll
    for (int it = 0; it < 8; ++it) {
        const int work = t + 256 * it;       // 0..2047
        const int d4 = work & 7;             // float4 index along D
        const int ww = (work >> 3) & 15;     // window col
        const int wh = work >> 7;            // window row
        const int base = wh * 2048 + ww * 64 + d4 * 4; // (2*wh)*1024 + (2*ww)*32 + 4*d4

        const float4 a0 = *reinterpret_cast<const float4*>(p + base);          // (h0, w0)
        const float4 a1 = *reinterpret_cast<const float4*>(p + base + 32);     // (h0, w1)
        const float4 a2 = *reinterpret_cast<const float4*>(p + base + 1024);   // (h1, w0)
        const float4 a3 = *reinterpret_cast<const float4*>(p + base + 1056);   // (h1, w1)

        float mx = fmaxf(fmaxf(a0.x, a1.x), fmaxf(a2.x, a3.x));
        float my = fmaxf(fmaxf(a0.y, a1.y), fmaxf(a2.y, a3.y));
        float mz = fmaxf(fmaxf(a0.z, a1.z), fmaxf(a2.z, a3.z));
        float mw = fmaxf(fmaxf(a0.w, a1.w), fmaxf(a2.w, a3.w));

        float s = (a0.x + a0.y) + (a0.z + a0.w)
                + (a1.x + a1.y) + (a1.z + a1.w)
                + (a2.x + a2.y) + (a2.z + a2.w)
                + (a3.x + a3.y) + (a3.z + a3.w);

        acc += fmaxf(mx, my) + fmaxf(mz, mw) + s * 0.125f;
    }

    // Block reduction: wave shuffle then LDS across 4 waves.
#pragma unroll
    for (int off = 32; off > 0; off >>= 1) acc += __shfl_down(acc, off);

    __shared__ float red[4];
    const int wave = t >> 6;
    if ((t & 63) == 0) red[wave] = acc;
    __syncthreads();
    if (t == 0) {
        ws[which * BC_TOTAL + bc] = (red[0] + red[1]) + (red[2] + red[3]);
    }
}

__global__ __launch_bounds__(256) void finalize_kernel(
    const float* __restrict__ ws, float* __restrict__ out)
{
    const int b = blockIdx.x;   // 0..3
    const int c = threadIdx.x;  // 0..255
    const int bc = b * 256 + c;

    const float Sx = ws[bc];
    const float Sy = ws[BC_TOTAL + bc];
    const float Sz = ws[2 * BC_TOTAL + bc];

    const float xy = Sx + Sy;
    const float yz = Sy + Sz;
    const float xz = Sx + Sz;
    const float pooled = xy * xy + yz * yz + xz * xz;

    float sq = pooled * pooled;
#pragma unroll
    for (int off = 32; off > 0; off >>= 1) sq += __shfl_down(sq, off);

    __shared__ float red[4];
    if ((c & 63) == 0) red[c >> 6] = sq;
    __syncthreads();

    __shared__ float norm_s;
    if (c == 0) norm_s = sqrtf((red[0] + red[1]) + (red[2] + red[3]));
    __syncthreads();

    const float norm = fmaxf(norm_s, 1e-12f);
    out[bc] = pooled / norm;
}

extern "C" void kernel_launch(void* const* d_in, const int* in_sizes, int n_in,
                              void* d_out, int out_size, void* d_ws, size_t ws_size,
                              hipStream_t stream) {
    const float* x = (const float*)d_in[0];
    const float* y = (const float*)d_in[1];
    const float* z = (const float*)d_in[2];
    float* ws = (float*)d_ws;      // 3 * 1024 floats of partial sums
    float* out = (float*)d_out;    // 1024 floats (4 x 256)

    dim3 grid(BC_TOTAL, 3, 1);
    pool_sum_kernel<<<grid, 256, 0, stream>>>(x, y, z, ws);
    finalize_kernel<<<4, 256, 0, stream>>>(ws, out);
}